// Round 1
// baseline (1595.286 us; speedup 1.0000x reference)
//
#include <hip/hip_runtime.h>

// B=256, D0=16, D1=32, D2=64, D_FFN=2048, F1=2048, F2=1024
// 4 grouped GEMMs, all shapes divide the 128x128x64 tile exactly.

#define LDK 72  // padded LDS row (64 bf16 + 8 pad) -> breaks 16-way bank conflict

typedef __attribute__((ext_vector_type(8))) short bfrag;   // 8 bf16 (4 VGPRs)
typedef __attribute__((ext_vector_type(4))) float f4;      // 4 fp32 acc

__device__ __forceinline__ unsigned short f2bf(float f) {
  union { float f; unsigned u; } v; v.f = f;
  return (unsigned short)((v.u + 0x7fffu + ((v.u >> 16) & 1u)) >> 16);  // RNE
}

// Stage 128 rows x 64 k of fp32 -> bf16 into LDS. 2048 float4 items / 256 thr = 8 iters.
__device__ __forceinline__ void stage_f32(unsigned short* lds, const float* src,
                                          long rstride, int t) {
#pragma unroll
  for (int it = 0; it < 8; ++it) {
    int item = t + it * 256;
    int row = item >> 4, c4 = item & 15;
    float4 v = *(const float4*)(src + (long)row * rstride + c4 * 4);
    ushort4 o;
    o.x = f2bf(v.x); o.y = f2bf(v.y); o.z = f2bf(v.z); o.w = f2bf(v.w);
    *(ushort4*)(lds + row * LDK + c4 * 4) = o;
  }
}

// Stage 128 rows x 64 k of bf16 into LDS. 1024 16B items / 256 thr = 4 iters.
__device__ __forceinline__ void stage_bf16(unsigned short* lds, const unsigned short* src,
                                           long rstride, int t) {
#pragma unroll
  for (int it = 0; it < 4; ++it) {
    int item = t + it * 256;
    int row = item >> 3, c = item & 7;
    uint4 v = *(const uint4*)(src + (long)row * rstride + c * 8);
    *(uint4*)(lds + row * LDK + c * 8) = v;
  }
}

// C[M,N] = epi(A[M,K] @ W[N,K]^T + bias[N]) per group g = blockIdx.z.
// EPI 0: gelu(exact erf) -> bf16 store at out[g*grpO + m*o_rstride + n]
// EPI 1: fp32 store at same addressing (u buffer, x-layout)
// EPI 2: out[addr] = x[addr] + 0.5*(u[addr] + v), addr = g*64 + m*32768 + (n>>6)*2048 + (n&63)
template <bool ABF16, int EPI>
__global__ __launch_bounds__(256, 2) void gemm_bt(
    const void* Ab, long a_rstride, long a_k64, long grpA,
    const float* Wb, int K, long grpW,
    const float* biasb, long grpB,
    void* outb, long o_rstride, long grpO,
    const float* xin, const float* uin) {
  const int t = threadIdx.x;
  const int g = blockIdx.z;
  const int n0 = blockIdx.x * 128;
  const int m0 = blockIdx.y * 128;

  __shared__ unsigned short lds_a[128 * LDK];
  __shared__ unsigned short lds_b[128 * LDK];

  const float* W = Wb + (long)g * grpW + (long)n0 * K;
  const float* bias = biasb + (long)g * grpB + n0;

  f4 acc[4][4];
#pragma unroll
  for (int i = 0; i < 4; ++i)
#pragma unroll
    for (int j = 0; j < 4; ++j)
#pragma unroll
      for (int r = 0; r < 4; ++r) acc[i][j][r] = 0.f;

  const int lane = t & 63;
  const int wave = t >> 6;
  const int wm = (wave & 1) * 64;   // wave's 64x64 quadrant of the 128x128 tile
  const int wn = (wave >> 1) * 64;
  const int lr = lane & 15;         // A-row / B-col within 16
  const int lq = lane >> 4;         // quad -> k-offset lq*8

  const int nkt = K >> 6;
  for (int kt = 0; kt < nkt; ++kt) {
    if (ABF16) {
      const unsigned short* A = (const unsigned short*)Ab + (long)g * grpA +
                                (long)m0 * a_rstride + (long)kt * a_k64;
      stage_bf16(lds_a, A, a_rstride, t);
    } else {
      const float* A = (const float*)Ab + (long)g * grpA +
                       (long)m0 * a_rstride + (long)kt * a_k64;
      stage_f32(lds_a, A, a_rstride, t);
    }
    stage_f32(lds_b, W + kt * 64, K, t);
    __syncthreads();
#pragma unroll
    for (int ks = 0; ks < 2; ++ks) {
      bfrag af[4], bfv[4];
#pragma unroll
      for (int mt = 0; mt < 4; ++mt)
        af[mt] = *(const bfrag*)&lds_a[(wm + mt * 16 + lr) * LDK + ks * 32 + lq * 8];
#pragma unroll
      for (int nt = 0; nt < 4; ++nt)
        bfv[nt] = *(const bfrag*)&lds_b[(wn + nt * 16 + lr) * LDK + ks * 32 + lq * 8];
#pragma unroll
      for (int mt = 0; mt < 4; ++mt)
#pragma unroll
        for (int nt = 0; nt < 4; ++nt)
          acc[mt][nt] = __builtin_amdgcn_mfma_f32_16x16x32_bf16(af[mt], bfv[nt],
                                                                acc[mt][nt], 0, 0, 0);
    }
    __syncthreads();
  }

  // Epilogue. C/D layout (verified m89/m91): col = lane&15, row = (lane>>4)*4 + reg.
#pragma unroll
  for (int mt = 0; mt < 4; ++mt) {
#pragma unroll
    for (int nt = 0; nt < 4; ++nt) {
      int coll = wn + nt * 16 + lr;
      float bv = bias[coll];
#pragma unroll
      for (int r = 0; r < 4; ++r) {
        int rowg = m0 + wm + mt * 16 + lq * 4 + r;
        float v = acc[mt][nt][r] + bv;
        if (EPI == 0) {
          float gv = 0.5f * v * (1.0f + erff(v * 0.70710678118654752f));
          ((unsigned short*)outb)[(long)g * grpO + (long)rowg * o_rstride + (n0 + coll)] =
              f2bf(gv);
        } else if (EPI == 1) {
          ((float*)outb)[(long)g * grpO + (long)rowg * o_rstride + (n0 + coll)] = v;
        } else {
          int n = n0 + coll;
          long addr = (long)g * grpO + (long)rowg * 32768 +
                      (long)(n >> 6) * 2048 + (n & 63);
          ((float*)outb)[addr] = xin[addr] + 0.5f * (uin[addr] + v);
        }
      }
    }
  }
}

extern "C" void kernel_launch(void* const* d_in, const int* in_sizes, int n_in,
                              void* d_out, int out_size, void* d_ws, size_t ws_size,
                              hipStream_t stream) {
  const float* x    = (const float*)d_in[0];
  const float* W0_1 = (const float*)d_in[1];
  const float* b0_1 = (const float*)d_in[2];
  const float* W1_1 = (const float*)d_in[3];
  const float* b1_1 = (const float*)d_in[4];
  const float* W0_2 = (const float*)d_in[5];
  const float* b0_2 = (const float*)d_in[6];
  const float* W1_2 = (const float*)d_in[7];
  const float* b1_2 = (const float*)d_in[8];

  // workspace: h1 (bf16, 16MB) | h2 (bf16, 32MB) | u (fp32, 32MB) = 80 MB
  unsigned short* h1 = (unsigned short*)d_ws;
  unsigned short* h2 = h1 + (long)16 * 256 * 2048;
  float* u = (float*)(h2 + (long)32 * 256 * 2048);

  dim3 blk(256, 1, 1);

  // k1: h1[g] = gelu(x1[:,g,:] @ W0_1[g]^T + b0_1[g])   M=256,N=2048,K=2048, 16 groups
  gemm_bt<false, 0><<<dim3(16, 2, 16), blk, 0, stream>>>(
      x, 32768L, 64L, 2048L,
      W0_1, 2048, 2048L * 2048,
      b0_1, 2048L,
      h1, 2048L, 256L * 2048,
      nullptr, nullptr);

  // k3: h2[g] = gelu(x2[:,g,:] @ W0_2[g]^T + b0_2[g])   M=256,N=2048,K=1024, 32 groups
  //     A gather: x[b, i, g, d2] -> k-chunk stride 2048 per 64 k, group offset g*64
  gemm_bt<false, 0><<<dim3(16, 2, 32), blk, 0, stream>>>(
      x, 32768L, 2048L, 64L,
      W0_2, 1024, 2048L * 1024,
      b0_2, 2048L,
      h2, 2048L, 256L * 2048,
      nullptr, nullptr);

  // k2: u = h1 @ W1_1^T + b1_1  -> fp32 in x-layout      M=256,N=2048,K=2048, 16 groups
  gemm_bt<true, 1><<<dim3(16, 2, 16), blk, 0, stream>>>(
      h1, 2048L, 64L, 256L * 2048,
      W1_1, 2048, 2048L * 2048,
      b1_1, 2048L,
      u, 32768L, 2048L,
      nullptr, nullptr);

  // k4: out = x + 0.5*(u + h2 @ W1_2^T + b1_2)           M=256,N=1024,K=2048, 32 groups
  gemm_bt<true, 2><<<dim3(8, 2, 32), blk, 0, stream>>>(
      h2, 2048L, 64L, 256L * 2048,
      W1_2, 2048, 1024L * 2048,
      b1_2, 1024L,
      d_out, 0L, 64L,
      x, u);
}